// Round 1
// baseline (278.889 us; speedup 1.0000x reference)
//
#include <hip/hip_runtime.h>
#include <stdint.h>

// DVH global loss, MI355X.
// B=4 batches, N=2^21 voxels/batch, 500 bins over [0,75].
// loss = mean_{b,j} ( suffix_sum_{k>j}(hist_p[b]-hist_g[b])[k] / (maskcount_b+1e-6) )^2
// Only the DIFFERENCE histogram matters: d[i] = hist_p[i] - hist_g[i] (exact in ints).
//
// R(this): fuse the reduce into the hist kernel via last-arriving-block
// reduction (fence -> done counter -> last block reduces). Saves one
// dispatch + inter-kernel gap; reduce runs on L2-hot ws data.

#define NBINS 500
#define NHIST 501          // searchsorted index c in [0,500]; c>=1 for d>=0
#define BATCH 4
#define NPB (1 << 21)      // elements per batch
#define VPB (NPB / 4)      // float4 per batch
#define THREADS 1024
#define BLOCKS_PER_BATCH 128
#define STRIDE (BLOCKS_PER_BATCH * THREADS)   // 131072 float4s; VPB/STRIDE == 4
#define TOTAL_BLOCKS (BLOCKS_PER_BATCH * BATCH)

// workspace layout (int32):
//   hist_diff : [b*512 + i], i<501, b<4      (offset 0)
//   maskcount : [2048 + b]
//   done ctr  : [2052]
#define MC_OFF 2048
#define CTR_OFF 2052
#define WS_INTS 2056

__device__ __forceinline__ int bin_of(float d) {
    // c = # of fp32 bins k*STEP that are <= d  (jnp.linspace(0,75,500),
    // searchsorted side='right'); d >= 0 guaranteed.
    const float STEP = 75.0f / 499.0f;
    const float INV  = 499.0f / 75.0f;
    int k = (int)(d * INV);
    if (k > 499) k = 499;
    if ((float)k * STEP > d) --k;
    else if (k < 499 && (float)(k + 1) * STEP <= d) ++k;
    if ((float)k * STEP > d) --k;   // safety second pass (k>=0 since bins[0]=0<=d)
    return k + 1;                   // in [1,500]
}

__global__ __launch_bounds__(THREADS) void dvh_fused_kernel(
        const float4* __restrict__ dp, const float4* __restrict__ dg,
        const float4* __restrict__ dm, int* __restrict__ ws,
        float* __restrict__ out) {
    __shared__ int shd[NHIST];
    __shared__ unsigned int smc;
    __shared__ int lastflag;
    __shared__ int wtot[16];
    __shared__ float facc[16];

    const int b = blockIdx.y;
    const int t = threadIdx.x;
    for (int i = t; i < NHIST; i += THREADS) shd[i] = 0;
    if (t == 0) smc = 0u;
    __syncthreads();

    // Each thread owns exactly 4 float4s per array. Issue all 12 independent
    // loads before any use -> 12 outstanding vmem ops/thread (latency hiding
    // via ILP; prior session showed occupancy alone doesn't fix a serial loop).
    const size_t base = (size_t)b * VPB + blockIdx.x * THREADS + t;
    float4 m0 = dm[base];              float4 m1 = dm[base + STRIDE];
    float4 m2 = dm[base + 2 * STRIDE]; float4 m3 = dm[base + 3 * STRIDE];
    float4 p0 = dp[base];              float4 p1 = dp[base + STRIDE];
    float4 p2 = dp[base + 2 * STRIDE]; float4 p3 = dp[base + 3 * STRIDE];
    float4 g0 = dg[base];              float4 g1 = dg[base + STRIDE];
    float4 g2 = dg[base + 2 * STRIDE]; float4 g3 = dg[base + 3 * STRIDE];

    unsigned int myc = 0;
#define DO(mm, pp, gg) \
    if (mm != 0.0f) { atomicAdd(&shd[bin_of(pp)], 1); atomicAdd(&shd[bin_of(gg)], -1); ++myc; }
    DO(m0.x, p0.x, g0.x) DO(m0.y, p0.y, g0.y) DO(m0.z, p0.z, g0.z) DO(m0.w, p0.w, g0.w)
    DO(m1.x, p1.x, g1.x) DO(m1.y, p1.y, g1.y) DO(m1.z, p1.z, g1.z) DO(m1.w, p1.w, g1.w)
    DO(m2.x, p2.x, g2.x) DO(m2.y, p2.y, g2.y) DO(m2.z, p2.z, g2.z) DO(m2.w, p2.w, g2.w)
    DO(m3.x, p3.x, g3.x) DO(m3.y, p3.y, g3.y) DO(m3.z, p3.z, g3.z) DO(m3.w, p3.w, g3.w)
#undef DO
    if (myc) atomicAdd(&smc, myc);
    __syncthreads();

    // Drain per-block histogram into global difference histogram.
    for (int i = t; i < NHIST; i += THREADS) {
        int v = shd[i];
        if (v) atomicAdd(&ws[b * 512 + i], v);
    }
    if (t == 0 && smc) atomicAdd((unsigned int*)&ws[MC_OFF + b], smc);

    // ---- last-arriving-block reduction ----
    __threadfence();          // release this block's atomics to device scope
    __syncthreads();
    if (t == 0) {
        unsigned int old = atomicAdd((unsigned int*)&ws[CTR_OFF], 1u);
        lastflag = (old == TOTAL_BLOCKS - 1) ? 1 : 0;
    }
    __syncthreads();
    if (!lastflag) return;
    __threadfence();          // acquire: see all other blocks' atomics

    // Reduce: suffix-sum of diff hist per batch, squared-normalized sum.
    const int lane = t & 63;
    const int w = t >> 6;     // 16 waves
    float acc = 0.0f;

    for (int bb = 0; bb < BATCH; ++bb) {
        int v = (t < NHIST) ? ws[bb * 512 + t] : 0;
        // intra-wave inclusive scan (no barriers)
        #pragma unroll
        for (int off = 1; off < 64; off <<= 1) {
            int n = __shfl_up(v, off, 64);
            if (lane >= off) v += n;
        }
        if (lane == 63) wtot[w] = v;
        __syncthreads();
        int offset = 0, total = 0;
        #pragma unroll
        for (int i = 0; i < 16; ++i) {
            int x = wtot[i];
            total += x;
            if (i < w) offset += x;
        }
        const int prefix = v + offset;   // inclusive prefix over hist-diff[0..t]
        const float denom = (float)((unsigned int)ws[MC_OFF + bb]) + 1e-6f;
        if (t < NBINS) {
            // count_ge[j] diff = sum_{k>=j+1} d[k] = total - incl_prefix[j]
            float diff = (float)(total - prefix) / denom;
            acc += diff * diff;
        }
        __syncthreads();   // before wtot reuse next batch
    }

    // block reduction of acc
    #pragma unroll
    for (int off = 32; off > 0; off >>= 1) acc += __shfl_down(acc, off, 64);
    if (lane == 0) facc[w] = acc;
    __syncthreads();
    if (t == 0) {
        float s = 0.0f;
        #pragma unroll
        for (int i = 0; i < 16; ++i) s += facc[i];
        out[0] = s * (1.0f / (BATCH * NBINS));
    }
}

extern "C" void kernel_launch(void* const* d_in, const int* in_sizes, int n_in,
                              void* d_out, int out_size, void* d_ws, size_t ws_size,
                              hipStream_t stream) {
    const float4* dp = (const float4*)d_in[0];   // d_pred
    const float4* dg = (const float4*)d_in[1];   // d_gt
    const float4* dm = (const float4*)d_in[2];   // mask
    int* ws = (int*)d_ws;

    hipMemsetAsync(d_ws, 0, WS_INTS * sizeof(int), stream);

    dim3 grid(BLOCKS_PER_BATCH, BATCH);
    dvh_fused_kernel<<<grid, dim3(THREADS), 0, stream>>>(dp, dg, dm, ws, (float*)d_out);
}

// Round 2
// 125.724 us; speedup vs baseline: 2.2183x; 2.2183x over previous
//
#include <hip/hip_runtime.h>
#include <stdint.h>

// DVH global loss, MI355X.
// B=4 batches, N=2^21 voxels/batch, 500 bins over [0,75].
// loss = mean_{b,j} ( suffix_sum_{k>j}(hist_p[b]-hist_g[b])[k] / (maskcount_b+1e-6) )^2
// Only the DIFFERENCE histogram matters: d[i] = hist_p[i] - hist_g[i] (exact in ints).
//
// R1 lesson: __threadfence() (device-scope release fence) on gfx950 emits
// per-wave L2 writeback/invalidate (cross-XCD coherence) -> 201 us kernel.
// R2: fuse WITHOUT fences. All cross-block writes are device-scope atomics
// (coherent by default, m20); __syncthreads() drains vmcnt(0) per wave
// (compiler-guaranteed), so after the barrier all of this block's atomics
// are globally performed. Counter increment is a RELAXED device-scope
// atomic; the last block re-reads ws with agent-scope atomic loads
// (cache-bypassing) so no stale L1/L2 lines. Zero cache-maintenance ops.

#define NBINS 500
#define NHIST 501          // searchsorted index c in [0,500]; c>=1 for d>=0
#define BATCH 4
#define NPB (1 << 21)      // elements per batch
#define VPB (NPB / 4)      // float4 per batch
#define THREADS 1024
#define BLOCKS_PER_BATCH 128
#define STRIDE (BLOCKS_PER_BATCH * THREADS)   // 131072 float4s; VPB/STRIDE == 4
#define TOTAL_BLOCKS (BLOCKS_PER_BATCH * BATCH)

// workspace layout (int32):
//   hist_diff : [b*512 + i], i<501, b<4      (offset 0)
//   maskcount : [2048 + b]
//   done ctr  : [2052]
#define MC_OFF 2048
#define CTR_OFF 2052
#define WS_INTS 2056

__device__ __forceinline__ int bin_of(float d) {
    // c = # of fp32 bins k*STEP that are <= d  (jnp.linspace(0,75,500),
    // searchsorted side='right'); d >= 0 guaranteed.
    const float STEP = 75.0f / 499.0f;
    const float INV  = 499.0f / 75.0f;
    int k = (int)(d * INV);
    if (k > 499) k = 499;
    if ((float)k * STEP > d) --k;
    else if (k < 499 && (float)(k + 1) * STEP <= d) ++k;
    if ((float)k * STEP > d) --k;   // safety second pass (k>=0 since bins[0]=0<=d)
    return k + 1;                   // in [1,500]
}

__global__ __launch_bounds__(THREADS) void dvh_fused_kernel(
        const float4* __restrict__ dp, const float4* __restrict__ dg,
        const float4* __restrict__ dm, int* __restrict__ ws,
        float* __restrict__ out) {
    __shared__ int shd[NHIST];
    __shared__ unsigned int smc;
    __shared__ int lastflag;
    __shared__ int wtot[16];
    __shared__ float facc[16];

    const int b = blockIdx.y;
    const int t = threadIdx.x;
    for (int i = t; i < NHIST; i += THREADS) shd[i] = 0;
    if (t == 0) smc = 0u;
    __syncthreads();

    // Each thread owns exactly 4 float4s per array. Issue all 12 independent
    // loads before any use -> 12 outstanding vmem ops/thread (latency hiding
    // via ILP).
    const size_t base = (size_t)b * VPB + blockIdx.x * THREADS + t;
    float4 m0 = dm[base];              float4 m1 = dm[base + STRIDE];
    float4 m2 = dm[base + 2 * STRIDE]; float4 m3 = dm[base + 3 * STRIDE];
    float4 p0 = dp[base];              float4 p1 = dp[base + STRIDE];
    float4 p2 = dp[base + 2 * STRIDE]; float4 p3 = dp[base + 3 * STRIDE];
    float4 g0 = dg[base];              float4 g1 = dg[base + STRIDE];
    float4 g2 = dg[base + 2 * STRIDE]; float4 g3 = dg[base + 3 * STRIDE];

    unsigned int myc = 0;
#define DO(mm, pp, gg) \
    if (mm != 0.0f) { atomicAdd(&shd[bin_of(pp)], 1); atomicAdd(&shd[bin_of(gg)], -1); ++myc; }
    DO(m0.x, p0.x, g0.x) DO(m0.y, p0.y, g0.y) DO(m0.z, p0.z, g0.z) DO(m0.w, p0.w, g0.w)
    DO(m1.x, p1.x, g1.x) DO(m1.y, p1.y, g1.y) DO(m1.z, p1.z, g1.z) DO(m1.w, p1.w, g1.w)
    DO(m2.x, p2.x, g2.x) DO(m2.y, p2.y, g2.y) DO(m2.z, p2.z, g2.z) DO(m2.w, p2.w, g2.w)
    DO(m3.x, p3.x, g3.x) DO(m3.y, p3.y, g3.y) DO(m3.z, p3.z, g3.z) DO(m3.w, p3.w, g3.w)
#undef DO
    if (myc) atomicAdd(&smc, myc);
    __syncthreads();

    // Drain per-block histogram into global difference histogram (device-scope
    // atomics -> coherent at the device point, no fence needed).
    for (int i = t; i < NHIST; i += THREADS) {
        int v = shd[i];
        if (v) atomicAdd(&ws[b * 512 + i], v);
    }
    if (t == 0 && smc) atomicAdd((unsigned int*)&ws[MC_OFF + b], smc);

    // ---- last-arriving-block reduction (fence-free) ----
    // __syncthreads() drains vmcnt(0) for every wave in this block, so all of
    // this block's global atomics are performed device-wide before any thread
    // passes the barrier. (Belt-and-braces explicit drain first; it is free.)
    asm volatile("s_waitcnt vmcnt(0)" ::: "memory");
    __syncthreads();
    if (t == 0) {
        unsigned int old = atomicAdd((unsigned int*)&ws[CTR_OFF], 1u);  // relaxed, device-scope
        lastflag = (old == TOTAL_BLOCKS - 1) ? 1 : 0;
    }
    __syncthreads();
    if (!lastflag) return;

    // Last block: every other block's atomics are complete (they passed their
    // own vmcnt-draining barrier before incrementing the counter). Re-read ws
    // with agent-scope atomic loads so we bypass any stale local cache lines.
    const int lane = t & 63;
    const int w = t >> 6;     // 16 waves
    float acc = 0.0f;

    // Hoist all coherent loads up front (independent -> overlapped latency).
    int vv[BATCH];
    unsigned int mcv[BATCH];
    #pragma unroll
    for (int bb = 0; bb < BATCH; ++bb) {
        vv[bb] = (t < NHIST)
            ? __hip_atomic_load(&ws[bb * 512 + t], __ATOMIC_RELAXED, __HIP_MEMORY_SCOPE_AGENT)
            : 0;
        mcv[bb] = __hip_atomic_load((unsigned int*)&ws[MC_OFF + bb],
                                    __ATOMIC_RELAXED, __HIP_MEMORY_SCOPE_AGENT);
    }

    #pragma unroll
    for (int bb = 0; bb < BATCH; ++bb) {
        int v = vv[bb];
        // intra-wave inclusive scan (no barriers)
        #pragma unroll
        for (int off = 1; off < 64; off <<= 1) {
            int n = __shfl_up(v, off, 64);
            if (lane >= off) v += n;
        }
        if (lane == 63) wtot[w] = v;
        __syncthreads();
        int offset = 0, total = 0;
        #pragma unroll
        for (int i = 0; i < 16; ++i) {
            int x = wtot[i];
            total += x;
            if (i < w) offset += x;
        }
        const int prefix = v + offset;   // inclusive prefix over hist-diff[0..t]
        const float denom = (float)mcv[bb] + 1e-6f;
        if (t < NBINS) {
            // count_ge[j] diff = sum_{k>=j+1} d[k] = total - incl_prefix[j]
            float diff = (float)(total - prefix) / denom;
            acc += diff * diff;
        }
        __syncthreads();   // before wtot reuse next batch
    }

    // block reduction of acc
    #pragma unroll
    for (int off = 32; off > 0; off >>= 1) acc += __shfl_down(acc, off, 64);
    if (lane == 0) facc[w] = acc;
    __syncthreads();
    if (t == 0) {
        float s = 0.0f;
        #pragma unroll
        for (int i = 0; i < 16; ++i) s += facc[i];
        out[0] = s * (1.0f / (BATCH * NBINS));
    }
}

extern "C" void kernel_launch(void* const* d_in, const int* in_sizes, int n_in,
                              void* d_out, int out_size, void* d_ws, size_t ws_size,
                              hipStream_t stream) {
    const float4* dp = (const float4*)d_in[0];   // d_pred
    const float4* dg = (const float4*)d_in[1];   // d_gt
    const float4* dm = (const float4*)d_in[2];   // mask
    int* ws = (int*)d_ws;

    hipMemsetAsync(d_ws, 0, WS_INTS * sizeof(int), stream);

    dim3 grid(BLOCKS_PER_BATCH, BATCH);
    dvh_fused_kernel<<<grid, dim3(THREADS), 0, stream>>>(dp, dg, dm, ws, (float*)d_out);
}